// Round 1
// baseline (1420.886 us; speedup 1.0000x reference)
//
#include <hip/hip_runtime.h>

#define NHEADS 8
#define NNODES 100000
#define NSUM_OFF 64  // float offset of node_sum within ws (256B aligned)

// ---- order-preserving float<->uint encoding for atomicMax on signed floats
__device__ __forceinline__ unsigned fenc(float f) {
    unsigned u = __float_as_uint(f);
    return (u & 0x80000000u) ? ~u : (u | 0x80000000u);
}
__device__ __forceinline__ float fdec(unsigned u) {
    unsigned b = (u & 0x80000000u) ? (u ^ 0x80000000u) : ~u;
    return __uint_as_float(b);
}

// ---- pass 1: per-head max over edge_val [E,8], processed as float4 pairs
__global__ void __launch_bounds__(256) kmax(const float4* __restrict__ ev4,
                                            long long n4,
                                            unsigned* __restrict__ gmax) {
    const float NEG = -3.402823466e38f;
    float4 mv = make_float4(NEG, NEG, NEG, NEG);
    long long tid = blockIdx.x * (long long)blockDim.x + threadIdx.x;
    long long stride = (long long)gridDim.x * blockDim.x;
    for (long long i = tid; i < n4; i += stride) {
        float4 v = ev4[i];
        mv.x = fmaxf(mv.x, v.x);
        mv.y = fmaxf(mv.y, v.y);
        mv.z = fmaxf(mv.z, v.z);
        mv.w = fmaxf(mv.w, v.w);
    }
    // parity: even tid holds heads 0..3, odd tid holds heads 4..7 (stride is even)
    float4 ov;
    ov.x = __shfl_xor(mv.x, 1);
    ov.y = __shfl_xor(mv.y, 1);
    ov.z = __shfl_xor(mv.z, 1);
    ov.w = __shfl_xor(mv.w, 1);
    float m8[8];
    if ((tid & 1) == 0) {
        m8[0] = mv.x; m8[1] = mv.y; m8[2] = mv.z; m8[3] = mv.w;
        m8[4] = ov.x; m8[5] = ov.y; m8[6] = ov.z; m8[7] = ov.w;
    } else {
        m8[0] = ov.x; m8[1] = ov.y; m8[2] = ov.z; m8[3] = ov.w;
        m8[4] = mv.x; m8[5] = mv.y; m8[6] = mv.z; m8[7] = mv.w;
    }
#pragma unroll
    for (int h = 0; h < 8; ++h) {
#pragma unroll
        for (int off = 2; off < 64; off <<= 1)
            m8[h] = fmaxf(m8[h], __shfl_xor(m8[h], off));
    }
    __shared__ float sm[4][8];
    int wid = threadIdx.x >> 6;
    int lane = threadIdx.x & 63;
    if (lane == 0) {
#pragma unroll
        for (int h = 0; h < 8; ++h) sm[wid][h] = m8[h];
    }
    __syncthreads();
    if (threadIdx.x < 8) {
        float v = sm[0][threadIdx.x];
#pragma unroll
        for (int w = 1; w < 4; ++w) v = fmaxf(v, sm[w][threadIdx.x]);
        atomicMax(&gmax[threadIdx.x], fenc(v));
    }
}

// ---- pass 1b: scale[h] = 0.5^k, k = max(ceil(log2(max(m,1e-30)/10)), 0) if m>10 else 0
__global__ void kscale(const unsigned* __restrict__ gmax, float* __restrict__ scale) {
    int h = threadIdx.x;
    if (h < NHEADS) {
        float m = fdec(gmax[h]);
        float k = (m > 10.0f) ? ceilf(log2f(fmaxf(m, 1e-30f) / 10.0f)) : 0.0f;
        k = fmaxf(k, 0.0f);
        scale[h] = exp2f(-k);
    }
}

// ---- pass 2: e = exp(edge_val*scale); atomicAdd into node_sum[row]
__global__ void __launch_bounds__(256) kexp(const float4* __restrict__ ev4,
                                            const int* __restrict__ row,
                                            const float* __restrict__ scale,
                                            float* __restrict__ nsum,
                                            long long n4) {
    float4 sLo = *(const float4*)scale;
    float4 sHi = *(const float4*)(scale + 4);
    long long tid = blockIdx.x * (long long)blockDim.x + threadIdx.x;
    long long stride = (long long)gridDim.x * blockDim.x;
    for (long long i = tid; i < n4; i += stride) {
        float4 v = ev4[i];
        long long e = i >> 1;
        int hb = ((int)i & 1) << 2;
        int r = row[e];
        float4 s = (i & 1) ? sHi : sLo;
        float* base = nsum + (long long)r * NHEADS + hb;
        unsafeAtomicAdd(base + 0, expf(v.x * s.x));
        unsafeAtomicAdd(base + 1, expf(v.y * s.y));
        unsafeAtomicAdd(base + 2, expf(v.z * s.z));
        unsafeAtomicAdd(base + 3, expf(v.w * s.w));
    }
}

// ---- pass 3: out = exp(edge_val*scale) / node_sum[row]
__global__ void __launch_bounds__(256) kout(const float4* __restrict__ ev4,
                                            const int* __restrict__ row,
                                            const float* __restrict__ scale,
                                            const float* __restrict__ nsum,
                                            float4* __restrict__ out4,
                                            long long n4) {
    float4 sLo = *(const float4*)scale;
    float4 sHi = *(const float4*)(scale + 4);
    long long tid = blockIdx.x * (long long)blockDim.x + threadIdx.x;
    long long stride = (long long)gridDim.x * blockDim.x;
    for (long long i = tid; i < n4; i += stride) {
        float4 v = ev4[i];
        long long e = i >> 1;
        int hb = ((int)i & 1) << 2;
        int r = row[e];
        float4 s = (i & 1) ? sHi : sLo;
        const float4 ns = *(const float4*)(nsum + (long long)r * NHEADS + hb);
        float4 o;
        o.x = expf(v.x * s.x) / ns.x;
        o.y = expf(v.y * s.y) / ns.y;
        o.z = expf(v.z * s.z) / ns.z;
        o.w = expf(v.w * s.w) / ns.w;
        out4[i] = o;
    }
}

extern "C" void kernel_launch(void* const* d_in, const int* in_sizes, int n_in,
                              void* d_out, int out_size, void* d_ws, size_t ws_size,
                              hipStream_t stream) {
    const float* ev = (const float*)d_in[0];
    const int* row = (const int*)d_in[1];
    long long nElem = (long long)in_sizes[0];  // E * 8
    long long n4 = nElem >> 2;                 // float4 count

    float* ws = (float*)d_ws;
    unsigned* gmax = (unsigned*)ws;   // [8]  encoded maxes
    float* scale = ws + 8;            // [8]
    float* nsum = ws + NSUM_OFF;      // [NNODES*8]

    // zero max slots + node_sum every call (ws is not re-poisoned between replays)
    hipMemsetAsync(d_ws, 0, (NSUM_OFF + (size_t)NNODES * NHEADS) * sizeof(float), stream);

    kmax<<<1024, 256, 0, stream>>>((const float4*)ev, n4, gmax);
    kscale<<<1, 64, 0, stream>>>(gmax, scale);
    kexp<<<4096, 256, 0, stream>>>((const float4*)ev, row, scale, nsum, n4);
    kout<<<4096, 256, 0, stream>>>((const float4*)ev, row, scale, nsum, (float4*)d_out, n4);
}